// Round 1
// 370.209 us; speedup vs baseline: 1.2690x; 1.2690x over previous
//
#include <hip/hip_runtime.h>
#include <stdint.h>

#define KCB 196560   // codebook rows
#define DIM 24       // embed dim
#define BB  2        // batch
#define ZEL 12288    // B*D*16*16
#define NRB 384      // row-blocks for MFMA score (384*512 = 196608 >= 196560)
#define RBS 512      // rows per score block

typedef __attribute__((ext_vector_type(8)))  __bf16 bf16x8;
typedef __attribute__((ext_vector_type(16))) float  f32x16;

__device__ __forceinline__ unsigned long long pack_key(float sim, int idx) {
  unsigned u = __float_as_uint(sim);
  u = (u & 0x80000000u) ? ~u : (u | 0x80000000u);       // order-preserving float->u32
  return ((unsigned long long)u << 32) | (unsigned)(~(unsigned)idx); // smaller idx wins ties
}

// ---------- init: residual = z, zero the whole output (verbatim) ----------
__global__ __launch_bounds__(256) void init_kernel(const float* __restrict__ z,
    float* __restrict__ residual, float* __restrict__ out, int outTotal) {
  int e = blockIdx.x * 256 + threadIdx.x;
  if (e < ZEL) residual[e] = z[e];
  if (e < outTotal) out[e] = 0.0f;
}

// ---------- downsample residual -> rdown tokens (verbatim) ----------
__global__ __launch_bounds__(256) void down_kernel(const float* __restrict__ residual,
    float* __restrict__ rdown, unsigned long long* __restrict__ best, int t, int n) {
  int gid = blockIdx.x * 256 + threadIdx.x;
  if (gid < BB * n) best[gid] = 0ull;
  int total = BB * DIM * n;
  if (gid >= total) return;
  int sp = gid % n;
  int d  = (gid / n) % DIM;
  int b  = gid / (n * DIM);
  int oh = sp / t, ow = sp - oh * t;
  float inv_scale = 16.0f / (float)t;
  float ks = inv_scale;
  float sf_h = ((float)oh + 0.5f) * inv_scale - 0.5f;
  float sf_w = ((float)ow + 0.5f) * inv_scale - 0.5f;
  float wh[16], ww[16];
  float sh = 0.f, sw = 0.f;
#pragma unroll
  for (int i = 0; i < 16; ++i) {
    float vh = fmaxf(0.f, 1.f - fabsf(sf_h - (float)i) / ks);
    wh[i] = vh; sh += vh;
    float vw = fmaxf(0.f, 1.f - fabsf(sf_w - (float)i) / ks);
    ww[i] = vw; sw += vw;
  }
#pragma unroll
  for (int i = 0; i < 16; ++i) { wh[i] /= sh; ww[i] /= sw; }
  const float* resb = residual + (b * DIM + d) * 256;
  float acc = 0.f;
  for (int ih = 0; ih < 16; ++ih) {
    float ra = 0.f;
#pragma unroll
    for (int iw = 0; iw < 16; ++iw) ra = fmaf(ww[iw], resb[ih * 16 + iw], ra);
    acc = fmaf(wh[ih], ra, acc);
  }
  rdown[(b * n + sp) * DIM + d] = acc;
}

// ---------- helpers: split-bf16 (truncation) conversion ----------
__device__ __forceinline__ void load8(const float* p, float* xs) {
  float4 a = *(const float4*)p;
  float4 b = *(const float4*)(p + 4);
  xs[0]=a.x; xs[1]=a.y; xs[2]=a.z; xs[3]=a.w;
  xs[4]=b.x; xs[5]=b.y; xs[6]=b.z; xs[7]=b.w;
}

// x = hi + lo + r, |r| <= ~2^-14 |x|; hi/lo are truncated bf16
__device__ __forceinline__ void cvt_hi_lo(const float* xs, uint4& hw, uint4& lw) {
  unsigned h[8], l[8];
#pragma unroll
  for (int j = 0; j < 8; ++j) {
    unsigned b = __float_as_uint(xs[j]);
    h[j] = b >> 16;
    float hif = __uint_as_float(b & 0xffff0000u);
    float lof = xs[j] - hif;                    // exact in fp32
    l[j] = __float_as_uint(lof) >> 16;
  }
  hw = make_uint4(h[0] | (h[1] << 16), h[2] | (h[3] << 16),
                  h[4] | (h[5] << 16), h[6] | (h[7] << 16));
  lw = make_uint4(l[0] | (l[1] << 16), l[2] | (l[3] << 16),
                  l[4] | (l[5] << 16), l[6] | (l[7] << 16));
}

// ---------- MFMA score: per-token, per-512-row-block approx max similarity ----------
// Split-bf16 GEMM: sim ~ a_hi.b_hi + a_lo.b_hi + a_hi.b_lo ; K padded 24->32.
// A frag (codebook): row = lane&31, k = 8*(lane>>5)+j.  B frag (tokens): col = lane&31, same k.
// D: col = lane&31 (token), row = (reg&3)+8*(reg>>2)+4*(lane>>5) (codebook row).
__global__ __launch_bounds__(256) void score_kernel(const float* __restrict__ rdown,
    const float* __restrict__ cb, float* __restrict__ blockmax, int T) {
  const int bx = blockIdx.x;
  const int rb = bx % NRB, tb = bx / NRB;
  const int tid = threadIdx.x, lane = tid & 63, wv = tid >> 6;
  const int col = lane & 31, g = lane >> 5;
  const int tbase = tb * 128;
  const int ntt = min(4, (T - tbase + 31) >> 5);

  // --- token (B) fragments, persistent in registers ---
  bf16x8 bhi[4][2], blo[4][2];
#pragma unroll
  for (int tt = 0; tt < 4; ++tt) {
    int token = tbase + tt * 32 + col;
    bool tv = (tt < ntt) && (token < T);
    const float* tr = rdown + token * DIM;
    uint4 h0 = make_uint4(0,0,0,0), l0 = h0, h1 = h0, l1 = h0;
    if (tv) { float xs[8]; load8(tr + g * 8, xs); cvt_hi_lo(xs, h0, l0); }       // k 0..15
    if (tv && g == 0) { float xs[8]; load8(tr + 16, xs); cvt_hi_lo(xs, h1, l1); } // k 16..23 (g1 -> pad 0)
    bhi[tt][0] = __builtin_bit_cast(bf16x8, h0);
    blo[tt][0] = __builtin_bit_cast(bf16x8, l0);
    bhi[tt][1] = __builtin_bit_cast(bf16x8, h1);
    blo[tt][1] = __builtin_bit_cast(bf16x8, l1);
  }

  const f32x16 fzero = {};   // persistent zero bank: used as C-in of first MFMA (no per-tile movs)
  float runmax[4] = {-3.402823466e38f, -3.402823466e38f, -3.402823466e38f, -3.402823466e38f};
  const int rbase = rb * RBS + wv * 128;

#pragma unroll
  for (int rt = 0; rt < 4; ++rt) {
    int tilebase = rbase + rt * 32;
    if (tilebase >= KCB) continue;               // wave-uniform
    int row = tilebase + col;
    bool rv = row < KCB;
    const float* cr = cb + (size_t)row * DIM;
    uint4 h0 = make_uint4(0,0,0,0), l0 = h0, h1 = h0, l1 = h0;
    if (rv) { float xs[8]; load8(cr + g * 8, xs); cvt_hi_lo(xs, h0, l0); }
    if (rv && g == 0) { float xs[8]; load8(cr + 16, xs); cvt_hi_lo(xs, h1, l1); }
    bf16x8 ah0 = __builtin_bit_cast(bf16x8, h0);
    bf16x8 al0 = __builtin_bit_cast(bf16x8, l0);
    bf16x8 ah1 = __builtin_bit_cast(bf16x8, h1);
    bf16x8 al1 = __builtin_bit_cast(bf16x8, l1);
    int limit = KCB - tilebase;                  // >= 32 except the single partial tile
    bool full = limit >= 32;
#pragma unroll
    for (int tt = 0; tt < 4; ++tt) {
      if (tt >= ntt) continue;
      f32x16 acc = __builtin_amdgcn_mfma_f32_32x32x16_bf16(ah0, bhi[tt][0], fzero, 0, 0, 0);
      acc = __builtin_amdgcn_mfma_f32_32x32x16_bf16(ah1, bhi[tt][1], acc, 0, 0, 0);
      acc = __builtin_amdgcn_mfma_f32_32x32x16_bf16(al0, bhi[tt][0], acc, 0, 0, 0);
      acc = __builtin_amdgcn_mfma_f32_32x32x16_bf16(al1, bhi[tt][1], acc, 0, 0, 0);
      acc = __builtin_amdgcn_mfma_f32_32x32x16_bf16(ah0, blo[tt][0], acc, 0, 0, 0);
      acc = __builtin_amdgcn_mfma_f32_32x32x16_bf16(ah1, blo[tt][1], acc, 0, 0, 0);
      float m;
      if (full) {
        float m01 = fmaxf(acc[0], acc[1]),  m23 = fmaxf(acc[2], acc[3]);
        float m45 = fmaxf(acc[4], acc[5]),  m67 = fmaxf(acc[6], acc[7]);
        float m89 = fmaxf(acc[8], acc[9]),  mab = fmaxf(acc[10], acc[11]);
        float mcd = fmaxf(acc[12], acc[13]), mef = fmaxf(acc[14], acc[15]);
        m = fmaxf(fmaxf(fmaxf(m01, m23), fmaxf(m45, m67)),
                  fmaxf(fmaxf(m89, mab), fmaxf(mcd, mef)));
      } else {
        m = -3.402823466e38f;                    // mask rows >= KCB so sims can't be fake 0
#pragma unroll
        for (int r = 0; r < 16; ++r) {
          int rowid = (r & 3) + 8 * (r >> 2) + 4 * g;
          if (rowid < limit) m = fmaxf(m, acc[r]);
        }
      }
      runmax[tt] = fmaxf(runmax[tt], m);
    }
  }

  __shared__ float lmax[4][4][32];
#pragma unroll
  for (int tt = 0; tt < 4; ++tt) {
    float v = fmaxf(runmax[tt], __shfl_xor(runmax[tt], 32));
    if (lane < 32) lmax[wv][tt][col] = v;
  }
  __syncthreads();
  if (tid < 128) {
    int tt = tid >> 5, c = tid & 31;
    if (tt < ntt) {
      float m = fmaxf(fmaxf(lmax[0][tt][c], lmax[1][tt][c]),
                      fmaxf(lmax[2][tt][c], lmax[3][tt][c]));
      int token = tbase + tt * 32 + c;
      if (token < T) blockmax[token * NRB + rb] = m;
    }
  }
}

// ---------- exact finalize: prune by blockmax, rescan candidates with the EXACT
// ascending-k fmaf chain + strict-> / lowest-index tie-break (bit-identical to old kernel) ----
__global__ __launch_bounds__(256) void finalize_kernel(const float* __restrict__ cb,
    const float* __restrict__ rdown, const float* __restrict__ blockmax,
    unsigned long long* __restrict__ best, int T) {
  int tid = threadIdx.x, lane = tid & 63, wv = tid >> 6;
  int tok = blockIdx.x * 4 + wv;                 // one wave per token
  if (tok >= T) return;

  float x = (lane < DIM) ? rdown[tok * DIM + lane] : 0.f;
  float av[DIM];
#pragma unroll
  for (int k = 0; k < DIM; ++k)
    av[k] = __uint_as_float(__builtin_amdgcn_readlane(__float_as_uint(x), k));
  float ss = 0.f;
#pragma unroll
  for (int k = 0; k < DIM; ++k) ss = fmaf(av[k], av[k], ss);
  // eps = 1e-3*|a| >= 5x the split-bf16 error bound (3*2^-14*|a|): true argmax block provably kept
  float eps = 1e-3f * sqrtf(ss) + 1e-30f;

  const float* bmrow = blockmax + (size_t)tok * NRB;
  float bv[6];
#pragma unroll
  for (int i = 0; i < 6; ++i) bv[i] = bmrow[lane + 64 * i];   // 384 = 64*6
  float M = fmaxf(fmaxf(fmaxf(bv[0], bv[1]), fmaxf(bv[2], bv[3])), fmaxf(bv[4], bv[5]));
#pragma unroll
  for (int d = 32; d; d >>= 1) M = fmaxf(M, __shfl_xor(M, d));
  float thr = M - eps;

  unsigned long long bk = 0ull;
#pragma unroll
  for (int i = 0; i < 6; ++i) {
    unsigned long long mask = __ballot(bv[i] >= thr);
    while (mask) {                                // wave-uniform loop, expected ~1 iter total
      int l = __ffsll((unsigned long long)mask) - 1;
      mask &= mask - 1;
      int rowb = (l + 64 * i) * RBS;
      for (int r8 = 0; r8 < 8; ++r8) {
        int row = rowb + r8 * 64 + lane;
        if (row < KCB) {
          const float* cv = cb + (size_t)row * DIM;
          float acc = 0.f;
#pragma unroll
          for (int k = 0; k < DIM; ++k) acc = fmaf(av[k], cv[k], acc);  // exact chain
          unsigned long long key = pack_key(acc, row);
          if (key > bk) bk = key;                 // rows ascend per lane -> lowest idx kept
        }
      }
    }
  }
#pragma unroll
  for (int d = 32; d; d >>= 1) {
    unsigned long long o = __shfl_xor(bk, d);
    if (o > bk) bk = o;
  }
  if (lane == 0) best[tok] = bk;
}

// ---------- update (verbatim): gather zq, upsample, z_hat/residual, indices ----------
template<int TSZ>
__global__ __launch_bounds__(256) void update_kernel(const float* __restrict__ cb,
    const unsigned long long* __restrict__ best, float* __restrict__ residual,
    float* __restrict__ out, int idxBase) {
  constexpr int N = TSZ * TSZ;
  constexpr int T = BB * N;
  __shared__ float zq[T * DIM];
  int tid = threadIdx.x;
  for (int slot = tid; slot < T; slot += 256) {
    unsigned long long key = best[slot];
    int idx = (int)(~(unsigned)key);
    const float* cv = cb + (long long)idx * DIM;
    float v[DIM]; float ss = 0.f;
#pragma unroll
    for (int k = 0; k < DIM; ++k) { v[k] = cv[k]; ss = fmaf(v[k], v[k], ss); }
    float nrm = sqrtf(ss);
#pragma unroll
    for (int k = 0; k < DIM; ++k) zq[slot * DIM + k] = v[k] / nrm;
    if (blockIdx.x == 0) out[idxBase + slot] = (float)idx;
  }
  __syncthreads();
  int e = blockIdx.x * 256 + tid;
  int w = e & 15, h = (e >> 4) & 15;
  int d = (e >> 8) % DIM;
  int b = e / (DIM * 256);
  float inv_scale = (float)TSZ / 16.0f;
  float sf_h = ((float)h + 0.5f) * inv_scale - 0.5f;
  float sf_w = ((float)w + 0.5f) * inv_scale - 0.5f;
  float wh[TSZ], ww[TSZ];
  float sh = 0.f, sw = 0.f;
#pragma unroll
  for (int j = 0; j < TSZ; ++j) {
    float vh = fmaxf(0.f, 1.f - fabsf(sf_h - (float)j));
    wh[j] = vh; sh += vh;
    float vw = fmaxf(0.f, 1.f - fabsf(sf_w - (float)j));
    ww[j] = vw; sw += vw;
  }
#pragma unroll
  for (int j = 0; j < TSZ; ++j) { wh[j] /= sh; ww[j] /= sw; }
  const float* zb = zq + (b * N) * DIM + d;
  float acc = 0.f;
#pragma unroll
  for (int th = 0; th < TSZ; ++th) {
    float ra = 0.f;
#pragma unroll
    for (int tw = 0; tw < TSZ; ++tw) ra = fmaf(ww[tw], zb[(th * TSZ + tw) * DIM], ra);
    acc = fmaf(wh[th], ra, acc);
  }
  out[e] += acc;
  residual[e] -= acc;
}

// ---------- host ----------
extern "C" void kernel_launch(void* const* d_in, const int* in_sizes, int n_in,
                              void* d_out, int out_size, void* d_ws, size_t ws_size,
                              hipStream_t stream) {
  const float* z  = (const float*)d_in[0];
  const float* cb = (const float*)d_in[1];
  float* out = (float*)d_out;
  float* residual = (float*)d_ws;                          // 12288 f
  float* rdown = residual + ZEL;                           // 12288 f
  float* blockmax = rdown + ZEL;                           // 512*384 f = 786 KB
  unsigned long long* best =
      (unsigned long long*)(blockmax + 512 * NRB);         // 512 u64

  static const int TS[10] = {1, 2, 3, 4, 5, 6, 8, 10, 13, 16};

  init_kernel<<<(out_size + 255) / 256, 256, 0, stream>>>(z, residual, out, out_size);

  int prefix = 0;
  for (int s = 0; s < 10; ++s) {
    int t = TS[s], n = t * t, T = BB * n;
    int dtotal = BB * DIM * n;
    down_kernel<<<(dtotal + 255) / 256, 256, 0, stream>>>(residual, rdown, best, t, n);

    int ntb = (T + 127) >> 7;
    score_kernel<<<NRB * ntb, 256, 0, stream>>>(rdown, cb, blockmax, T);
    finalize_kernel<<<(T + 3) / 4, 256, 0, stream>>>(cb, rdown, blockmax, best, T);

    int idxBase = ZEL + BB * prefix;
    switch (t) {
      case 1:  update_kernel<1><<<48, 256, 0, stream>>>(cb, best, residual, out, idxBase); break;
      case 2:  update_kernel<2><<<48, 256, 0, stream>>>(cb, best, residual, out, idxBase); break;
      case 3:  update_kernel<3><<<48, 256, 0, stream>>>(cb, best, residual, out, idxBase); break;
      case 4:  update_kernel<4><<<48, 256, 0, stream>>>(cb, best, residual, out, idxBase); break;
      case 5:  update_kernel<5><<<48, 256, 0, stream>>>(cb, best, residual, out, idxBase); break;
      case 6:  update_kernel<6><<<48, 256, 0, stream>>>(cb, best, residual, out, idxBase); break;
      case 8:  update_kernel<8><<<48, 256, 0, stream>>>(cb, best, residual, out, idxBase); break;
      case 10: update_kernel<10><<<48, 256, 0, stream>>>(cb, best, residual, out, idxBase); break;
      case 13: update_kernel<13><<<48, 256, 0, stream>>>(cb, best, residual, out, idxBase); break;
      case 16: update_kernel<16><<<48, 256, 0, stream>>>(cb, best, residual, out, idxBase); break;
    }
    prefix += n;
  }
}